// Round 8
// baseline (363.231 us; speedup 1.0000x reference)
//
#include <hip/hip_runtime.h>

#define HDIM 32
#define NBINS 512   // lengths occupy bins 0..256; padded to pow2 for the scan

typedef _Float16 f16x8 __attribute__((ext_vector_type(8)));
typedef float f32x4 __attribute__((ext_vector_type(4)));
typedef unsigned int u32x4 __attribute__((ext_vector_type(4)));
#define MFMA16(A,B,C) __builtin_amdgcn_mfma_f32_16x16x32_f16((A),(B),(C),0,0,0)

// pack two f32 -> one u32 of 2 f16 (v_cvt_pkrtz_f16_f32, single VALU op)
__device__ __forceinline__ unsigned int pk_f16(float a, float b) {
    return __builtin_bit_cast(unsigned int, __builtin_amdgcn_cvt_pkrtz(a, b));
}

// ---- 1-transcendental tanh ----
// acc = 2*log2(e)*z (scale folded into weights). Then
//   tanh(z) = sign(z) * g(u),  u = exp2(-|acc|) = e^(-2|z|) in (0,1],
//   g(u) = (1-u)/(1+u)  ~= deg-4 minimax poly (Chebyshev of 1/(3+t),
//   pole at u=-1 -> coeffs decay 5.83^-n; max err 4.2e-4, below the
//   f16-H rounding ~1e-3). Saturation free: u underflow -> g -> G0.
// Cost/elem: exp2(12, -|.| via input mods) + 4 fma(8) + bfi(2) = 22 cyc
// vs exp2+add+rcp+fma = 28. tanh was 77% of the measured 290 cyc/step.
#define G0 0.9994880f
#define G1 (-1.9722120f)
#define G2 1.7439520f
#define G3 (-1.0846160f)
#define G4 0.3137470f
__device__ __forceinline__ float tanh1t(float acc) {
    const float u = __builtin_amdgcn_exp2f(-__builtin_fabsf(acc));
    const float p = fmaf(u, fmaf(u, fmaf(u, fmaf(u, G4, G3), G2), G1), G0);
    return copysignf(p, acc);   // v_bfi_b32; p >= 0 always
}

#define PIN8(a)  asm("" : "+v"(a[0]),"+v"(a[1]),"+v"(a[2]),"+v"(a[3]), \
                         "+v"(a[4]),"+v"(a[5]),"+v"(a[6]),"+v"(a[7]))
#define PIN4(a)  asm("" : "+v"(a[0]),"+v"(a[1]),"+v"(a[2]),"+v"(a[3]))

// ---- length-bucketing: counting sort into a permutation (DESCENDING) ----
__global__ __launch_bounds__(256) void hist_kernel(
    const int* __restrict__ l, int* __restrict__ cnt, int nseq)
{
    __shared__ int hc[NBINS];
    for (int k = threadIdx.x; k < NBINS; k += blockDim.x) hc[k] = 0;
    __syncthreads();
    for (int i = blockIdx.x * blockDim.x + threadIdx.x; i < nseq;
         i += gridDim.x * blockDim.x)
        atomicAdd(&hc[l[i]], 1);
    __syncthreads();
    for (int k = threadIdx.x; k < NBINS; k += blockDim.x)
        if (hc[k]) atomicAdd(&cnt[k], hc[k]);
}

// off[t] = sum_{k>t} cnt[k]  (exclusive SUFFIX sum -> longest lengths first)
__global__ __launch_bounds__(NBINS) void scan_kernel(
    const int* __restrict__ cnt, int* __restrict__ off)
{
    __shared__ int sc[NBINS];
    int t = threadIdx.x;
    int v0 = cnt[t];
    sc[t] = v0;
    __syncthreads();
    for (int d = 1; d < NBINS; d <<= 1) {
        int v = (t + d < NBINS) ? sc[t + d] : 0;
        __syncthreads();
        sc[t] += v;
        __syncthreads();
    }
    off[t] = sc[t] - v0;          // strictly-greater suffix sum
}

// Block-aggregated scatter: LDS histogram per block, ONE global atomic per
// touched bin to reserve a range, then LDS cursors for local ranks.
__global__ __launch_bounds__(256) void scatter_kernel(
    const int* __restrict__ l, int* __restrict__ off,
    int* __restrict__ perm, int nseq)
{
    __shared__ int lcur[NBINS];
    const int chunk = (nseq + gridDim.x - 1) / gridDim.x;
    const int lo = blockIdx.x * chunk;
    const int hi = min(nseq, lo + chunk);
    for (int k = threadIdx.x; k < NBINS; k += blockDim.x) lcur[k] = 0;
    __syncthreads();
    for (int i = lo + threadIdx.x; i < hi; i += blockDim.x)
        atomicAdd(&lcur[l[i]], 1);
    __syncthreads();
    for (int k = threadIdx.x; k < NBINS; k += blockDim.x) {
        int c = lcur[k];
        lcur[k] = c ? atomicAdd(&off[k], c) : 0;   // global base for this block
    }
    __syncthreads();
    for (int i = lo + threadIdx.x; i < hi; i += blockDim.x) {
        int p = atomicAdd(&lcur[l[i]], 1);         // LDS cursor = base + rank
        perm[p] = i;
    }
}

// ---- RNN: wave = 16 (length-matched) sequences, MFMA 16x16x32 f16 ----
// Structure identical to the passing round-7 kernel (8192 waves = 8/SIMD,
// sigma row permutation -> zero-cross-lane relayout). Only change: tanh1t
// (see above) replaces exp2+rcp tanh. r4-vs-r7 established the kernel is
// VALU-ISSUE-bound (dur independent of occupancy at fixed issue count;
// 290 cyc/step measured, tanh = 224 of it), so the predicted delta is
// proportional to issue reduction: 290 -> ~242 cyc/step.
//
// 16x16x32 fragment mappings (r7-verified):
//   A[m][k]: m = lane&15, k = 8*(lane>>4) + j
//   B[k][n]: n = lane&15, k = 8*(lane>>4) + j
//   C/D:     col n = lane&15, row m = 4*(lane>>4) + r
// sigma: tile0 rows sig0(m)=8*(m>>2)+(m&3), tile1 rows sig0(m)+4 ->
// lane (s,q)'s D regs are exactly its B k-slots {8q..8q+7}.
__global__ __launch_bounds__(64, 8) void rnn_kernel(
    const float* __restrict__ hin, const int* __restrict__ l,
    const int* __restrict__ perm,
    const float* __restrict__ W_ih, const float* __restrict__ W_hh,
    const float* __restrict__ b_ih, const float* __restrict__ b_hh,
    _Float16* __restrict__ emb, int nseq, int tmax)
{
    const int lane = threadIdx.x & 63;
    const int s    = lane & 15;          // seq within group; also A-row index
    const int q    = lane >> 4;          // k-quarter / D-row block

    const int pidx = blockIdx.x * 16 + s;
    const bool live = pidx < nseq;
    const int seq  = live ? perm[pidx] : 0;
    const int len  = live ? l[seq] : 0;

    const float S = 2.8853900817779268f;   // 2*log2(e), folded into weights

    // A fragments: tile0 = W_hh[sig0(m)][k]*S, tile1 = W_hh[sig0(m)+4][k]*S
    const int s0 = 8 * (s >> 2) + (s & 3);     // sig0(m) for m = s
    unsigned int q0[4], q1[4];
    {
        f16x8 w0, w1;
        #pragma unroll
        for (int j = 0; j < 8; ++j) {
            w0[j] = (_Float16)(W_hh[s0 * 32 + 8 * q + j] * S);
            w1[j] = (_Float16)(W_hh[(s0 + 4) * 32 + 8 * q + j] * S);
        }
        u32x4 a = __builtin_bit_cast(u32x4, w0);
        u32x4 b = __builtin_bit_cast(u32x4, w1);
        #pragma unroll
        for (int c = 0; c < 4; ++c) { q0[c] = a[c]; q1[c] = b[c]; }
    }
    PIN4(q0);
    PIN4(q1);
    const f16x8 A0 = __builtin_bit_cast(f16x8, (u32x4){q0[0], q0[1], q0[2], q0[3]});
    const f16x8 A1 = __builtin_bit_cast(f16x8, (u32x4){q1[0], q1[1], q1[2], q1[3]});

    // C-init constants: rows 8q+rr (rr=0..7); wv/bv scaled by S, pinned
    float wv[8], bv[8];
    #pragma unroll
    for (int rr = 0; rr < 8; ++rr) {
        const int row = 8 * q + rr;
        wv[rr] = W_ih[row] * S;
        bv[rr] = (b_ih[row] + b_hh[row]) * S;
    }
    PIN8(wv);
    PIN8(bv);

    // trip count = max length over the group's 16 seqs
    int mx = len;
    #pragma unroll
    for (int d = 1; d < 64; d <<= 1) {
        int o = __shfl_xor(mx, d);
        mx = mx > o ? mx : o;
    }
    const int maxlen = mx;

    // this lane owns emb row u32s [4q .. 4q+3] = h[8q .. 8q+7]
    unsigned int* po = (unsigned int*)emb + (size_t)seq * 16 + 4 * q;
    if (live && len == 0) {                 // len==0 -> emb stays zero
        *(u32x4*)po = (u32x4){0u, 0u, 0u, 0u};
    }

    const int base = seq * tmax;
    int off = len - 1;                      // x at step t = hin[len-1-t]
    float x0 = hin[base + (off > 0 ? off : 0)];
    float x1 = hin[base + (off - 1 > 0 ? off - 1 : 0)];

    u32x4 H = {0u, 0u, 0u, 0u};             // h, f16, B-fragment layout
    const int tstore = len - 1;

    for (int t = 0; t < maxlen; ++t) {
        const int off2 = off - 2;
        const float x2 = hin[base + (off2 > 0 ? off2 : 0)];   // prefetch

        f32x4 acc0, acc1;
        #pragma unroll
        for (int r = 0; r < 4; ++r) {
            acc0[r] = fmaf(x0, wv[r],     bv[r]);       // row 8q+r
            acc1[r] = fmaf(x0, wv[4 + r], bv[4 + r]);   // row 8q+4+r
        }
        const f16x8 Hf = __builtin_bit_cast(f16x8, H);
        acc0 = MFMA16(A0, Hf, acc0);
        acc1 = MFMA16(A1, Hf, acc1);

        // 1-trans tanh (poly in e^(-2|z|), sign via bfi)
        float hv[8];
        #pragma unroll
        for (int r = 0; r < 4; ++r) {
            hv[r]     = tanh1t(acc0[r]);
            hv[4 + r] = tanh1t(acc1[r]);
        }

        // sigma layout: D regs pack DIRECTLY into the B-fragment (k=8q+j)
        H = (u32x4){pk_f16(hv[0], hv[1]), pk_f16(hv[2], hv[3]),
                    pk_f16(hv[4], hv[5]), pk_f16(hv[6], hv[7])};

        if (t == tstore) *(u32x4*)po = H;   // last valid step: emit this seq

        x0 = x1; x1 = x2; --off;
    }
}

// ---- MLP, compile-time-specialized scalar version (round-4: passing, fast) ----
template<int FEATDIM, int ROUT>
__global__ __launch_bounds__(256) void mlp_spec_kernel(
    const _Float16* __restrict__ emb,
    const float* __restrict__ W1, const float* __restrict__ b1,
    const float* __restrict__ W2, const float* __restrict__ b2,
    const float* __restrict__ W3, const float* __restrict__ b3,
    float* __restrict__ out, int n)
{
    typedef _Float16 lf16x8 __attribute__((ext_vector_type(8)));
    __shared__ float sW1[FEATDIM * 32];
    __shared__ float sW2[32 * 32];
    __shared__ float sW3[32 * ROUT];
    __shared__ float sB[64 + ROUT];
    for (int k = threadIdx.x; k < FEATDIM * 32; k += 256) sW1[k] = W1[k];
    for (int k = threadIdx.x; k < 32 * 32;      k += 256) sW2[k] = W2[k];
    if (threadIdx.x < 32 * ROUT) sW3[threadIdx.x] = W3[threadIdx.x];
    if (threadIdx.x < 32)                 sB[threadIdx.x] = b1[threadIdx.x];
    else if (threadIdx.x < 64)            sB[threadIdx.x] = b2[threadIdx.x - 32];
    else if (threadIdx.x < 64 + ROUT)     sB[threadIdx.x] = b3[threadIdx.x - 64];
    __syncthreads();

    const int i = blockIdx.x * 256 + threadIdx.x;
    if (i >= n) return;
    const _Float16* f = emb + (size_t)i * FEATDIM;

    float z1[32];
    #pragma unroll
    for (int c = 0; c < 32; ++c) z1[c] = sB[c];
    #pragma unroll 2
    for (int k = 0; k < FEATDIM; k += 8) {
        const lf16x8 fv = *(const lf16x8*)(f + k);    // 16B coalesced load
        #pragma unroll
        for (int kk = 0; kk < 8; ++kk) {
            const float xk = (float)fv[kk];
            const float* wr = &sW1[(k + kk) * 32];    // uniform addr: broadcast
            #pragma unroll
            for (int c = 0; c < 32; c += 4) {
                const float4 w = *(const float4*)(wr + c);
                z1[c]     = fmaf(xk, w.x, z1[c]);
                z1[c + 1] = fmaf(xk, w.y, z1[c + 1]);
                z1[c + 2] = fmaf(xk, w.z, z1[c + 2]);
                z1[c + 3] = fmaf(xk, w.w, z1[c + 3]);
            }
        }
    }
    #pragma unroll
    for (int c = 0; c < 32; ++c) z1[c] = fmaxf(z1[c], 0.0f);

    float z2[32];
    #pragma unroll
    for (int c = 0; c < 32; ++c) z2[c] = sB[32 + c];
    #pragma unroll 4
    for (int j = 0; j < 32; ++j) {
        const float zj = z1[j];
        const float* wr = &sW2[j * 32];
        #pragma unroll
        for (int c = 0; c < 32; c += 4) {
            const float4 w = *(const float4*)(wr + c);
            z2[c]     = fmaf(zj, w.x, z2[c]);
            z2[c + 1] = fmaf(zj, w.y, z2[c + 1]);
            z2[c + 2] = fmaf(zj, w.z, z2[c + 2]);
            z2[c + 3] = fmaf(zj, w.w, z2[c + 3]);
        }
    }
    #pragma unroll
    for (int c = 0; c < 32; ++c) z2[c] = fmaxf(z2[c], 0.0f);

    float lo[ROUT];
    #pragma unroll
    for (int c = 0; c < ROUT; ++c) lo[c] = sB[64 + c];
    #pragma unroll
    for (int j = 0; j < 32; ++j) {
        const float zj = z2[j];
        #pragma unroll
        for (int c = 0; c < ROUT; ++c)
            lo[c] = fmaf(zj, sW3[j * ROUT + c], lo[c]);
    }
    if (ROUT == 4) {
        *(float4*)(out + (size_t)i * 4) = make_float4(lo[0], lo[1], lo[2], lo[3]);
    } else {
        #pragma unroll
        for (int c = 0; c < ROUT; ++c) out[(size_t)i * ROUT + c] = lo[c];
    }
}

// ---- generic fallback MLP (off-path for this problem) ----
__global__ __launch_bounds__(64) void mlp_kernel(
    const _Float16* __restrict__ emb,
    const float* __restrict__ W1, const float* __restrict__ b1,
    const float* __restrict__ W2, const float* __restrict__ b2,
    const float* __restrict__ W3, const float* __restrict__ b3,
    float* __restrict__ out, int n, int featdim, int rout)
{
    typedef _Float16 lf16x8 __attribute__((ext_vector_type(8)));
    extern __shared__ float smem[];
    float* sW1 = smem;
    float* sW2 = sW1 + featdim * 32;
    float* sW3 = sW2 + 1024;
    float* sB  = sW3 + 32 * rout;
    for (int k = threadIdx.x; k < featdim * 32; k += blockDim.x) sW1[k] = W1[k];
    for (int k = threadIdx.x; k < 1024;         k += blockDim.x) sW2[k] = W2[k];
    for (int k = threadIdx.x; k < 32 * rout;    k += blockDim.x) sW3[k] = W3[k];
    {
        int t = threadIdx.x;
        if (t < 32) {
            sB[t] = b1[t];
            if (t < rout) sB[64 + t] = b3[t];
        } else if (t < 64) {
            sB[t] = b2[t - 32];
        }
    }
    __syncthreads();

    int i = blockIdx.x * blockDim.x + threadIdx.x;
    if (i >= n) return;
    const _Float16* f = emb + (size_t)i * featdim;

    float z1[32];
    #pragma unroll
    for (int c = 0; c < 32; ++c) z1[c] = sB[c];
    for (int k = 0; k < featdim; k += 8) {
        lf16x8 fv = *(const lf16x8*)(f + k);
        #pragma unroll
        for (int kk = 0; kk < 8; ++kk) {
            const float xk = (float)fv[kk];
            const float* wr = &sW1[(k + kk) * 32];
            #pragma unroll
            for (int c = 0; c < 32; ++c) z1[c] = fmaf(xk, wr[c], z1[c]);
        }
    }
    #pragma unroll
    for (int c = 0; c < 32; ++c) z1[c] = fmaxf(z1[c], 0.0f);

    float z2[32];
    #pragma unroll
    for (int c = 0; c < 32; ++c) z2[c] = sB[32 + c];
    #pragma unroll
    for (int j = 0; j < 32; ++j) {
        const float zj = z1[j];
        const float* wr = &sW2[j * 32];
        #pragma unroll
        for (int c = 0; c < 32; ++c) z2[c] = fmaf(zj, wr[c], z2[c]);
    }
    #pragma unroll
    for (int c = 0; c < 32; ++c) z2[c] = fmaxf(z2[c], 0.0f);

    for (int c = 0; c < rout; ++c) {
        float lo = sB[64 + c];
        #pragma unroll
        for (int j = 0; j < 32; ++j) lo = fmaf(z2[j], sW3[j * rout + c], lo);
        out[(size_t)i * rout + c] = lo;
    }
}

extern "C" void kernel_launch(void* const* d_in, const int* in_sizes, int n_in,
                              void* d_out, int out_size, void* d_ws, size_t ws_size,
                              hipStream_t stream) {
    const float* h    = (const float*)d_in[0];
    const int*   l    = (const int*)d_in[1];
    const float* W_ih = (const float*)d_in[2];
    const float* W_hh = (const float*)d_in[3];
    const float* b_ih = (const float*)d_in[4];
    const float* b_hh = (const float*)d_in[5];
    const float* W1   = (const float*)d_in[6];
    const float* b1   = (const float*)d_in[7];
    const float* W2   = (const float*)d_in[8];
    const float* b2   = (const float*)d_in[9];
    const float* W3   = (const float*)d_in[10];
    const float* b3   = (const float*)d_in[11];
    float* out = (float*)d_out;

    const int nseq = in_sizes[1];               // N*R = 131072
    const int tmax = in_sizes[0] / nseq;        // 256
    const int rout = in_sizes[10] / 32;         // R = 4
    const int n    = nseq / rout;               // 32768
    const int featdim = rout * HDIM;            // 128

    // workspace layout: emb is f16 (8 MB)
    _Float16* emb = (_Float16*)d_ws;
    int* perm = (int*)((char*)d_ws + (size_t)nseq * HDIM * sizeof(_Float16));
    int* cnt  = perm + nseq;
    int* off  = cnt + NBINS;

    hipMemsetAsync(cnt, 0, NBINS * sizeof(int), stream);
    hist_kernel<<<64, 256, 0, stream>>>(l, cnt, nseq);
    scan_kernel<<<1, NBINS, 0, stream>>>(cnt, off);
    scatter_kernel<<<64, 256, 0, stream>>>(l, off, perm, nseq);

    // 16 seqs/wave, 1 wave/block: 8192 waves = 8/SIMD (hw max), desc order
    const int nblk = (nseq + 15) / 16;
    rnn_kernel<<<nblk, 64, 0, stream>>>(
        h, l, perm, W_ih, W_hh, b_ih, b_hh, emb, nseq, tmax);

    if (featdim == 128 && rout == 4) {
        mlp_spec_kernel<128, 4><<<(n + 255) / 256, 256, 0, stream>>>(
            emb, W1, b1, W2, b2, W3, b3, out, n);
    } else {
        const int smem_bytes =
            (featdim * 32 + 1024 + 32 * rout + 64 + 32) * sizeof(float);
        mlp_kernel<<<(n + 63) / 64, 64, smem_bytes, stream>>>(
            emb, W1, b1, W2, b2, W3, b3, out, n, featdim, rout);
    }
}